// Round 6
// baseline (302.382 us; speedup 1.0000x reference)
//
#include <hip/hip_runtime.h>

#define NPTS 65536
#define MM_BLOCKS 64

// packed-weight layout in d_ws (float offsets; lds copy is 16B-aligned)
#define WT_OFF   128   // packed weights start here (after minmax partials)
#define OFF_L1   0     // [j*4+i] w (i<3), [j*4+3]=b1[j]; j<3       -> 12
#define OFF_L2   16    // + 48*r : rows [jj*4+i] w, [jj*4+3]=bias; jj<10
#define OFF_MID  112   // + 544*l + 272*r : chunk c@120*c [jj*12+ii], bias@240+jj
#define OFF_L8   2832  // + 48*r : chunk c@12*c [ii], bias@24
#define PK_TOTAL 2928

// ---------------------------------------------------------------------------
// fast tanh: tanh(x) = 1 - 2/(e^{2x}+1).
// ---------------------------------------------------------------------------
__device__ __forceinline__ float fast_tanh(float x) {
  float e = __expf(2.0f * x);
  float r = __builtin_amdgcn_rcpf(e + 1.0f);
  return fmaf(-2.0f, r, 1.0f);
}

// pair cross-lane via DPP quad_perm (full-rate VALU, wave-synchronous):
// qswap: exchange with pair partner  [1,0,3,2] = 0xB1
// qpart: both lanes get partner-lane-1's value (pairs (0,1),(2,3)) [1,1,3,3]=0xF5
__device__ __forceinline__ float qswap(float x) {
  int i = __float_as_int(x);
  i = __builtin_amdgcn_update_dpp(i, i, 0xB1, 0xF, 0xF, false);
  return __int_as_float(i);
}
__device__ __forceinline__ float qpart(float x) {
  int i = __float_as_int(x);
  i = __builtin_amdgcn_update_dpp(i, i, 0xF5, 0xF, 0xF, false);
  return __int_as_float(i);
}

// ---------------------------------------------------------------------------
// Univariate order-3 jet.
// ---------------------------------------------------------------------------
struct J3 {
  float v, c1, c2, c3;
  __device__ __forceinline__ static J3 seed(float bias) {
    J3 z; z.v = bias; z.c1 = 0.f; z.c2 = 0.f; z.c3 = 0.f; return z;
  }
  __device__ __forceinline__ void macc(float w, const J3& o) {
    v  = fmaf(w, o.v,  v);
    c1 = fmaf(w, o.c1, c1);
    c2 = fmaf(w, o.c2, c2);
    c3 = fmaf(w, o.c3, c3);
  }
  __device__ __forceinline__ J3 chain() const {
    float s    = fast_tanh(v);
    float fp   = fmaf(-s, s, 1.0f);
    float fpp  = -2.0f * s * fp;
    float fppp = fmaf(6.0f * s, s, -2.0f) * fp;
    J3 r;
    r.v  = s;
    r.c1 = fp * c1;
    r.c2 = fmaf(fpp, c1 * c1, fp * c2);
    r.c3 = fmaf(fppp * c1, c1 * c1, fmaf(3.0f * fpp, c1 * c2, fp * c3));
    return r;
  }
  __device__ __forceinline__ static J3 swp(const J3& o) {
    J3 x; x.v = qswap(o.v); x.c1 = qswap(o.c1); x.c2 = qswap(o.c2); x.c3 = qswap(o.c3);
    return x;
  }
};

// ---------------------------------------------------------------------------
// Mixed second-order jet.
// ---------------------------------------------------------------------------
struct JM {
  float v, a, b, m;
  __device__ __forceinline__ static JM seed(float bias) {
    JM z; z.v = bias; z.a = 0.f; z.b = 0.f; z.m = 0.f; return z;
  }
  __device__ __forceinline__ void macc(float w, const JM& o) {
    v = fmaf(w, o.v, v);
    a = fmaf(w, o.a, a);
    b = fmaf(w, o.b, b);
    m = fmaf(w, o.m, m);
  }
  __device__ __forceinline__ JM chain() const {
    float s   = fast_tanh(v);
    float fp  = fmaf(-s, s, 1.0f);
    float fpp = -2.0f * s * fp;
    JM r;
    r.v = s;
    r.a = fp * a;
    r.b = fp * b;
    r.m = fmaf(fpp, a * b, fp * m);
    return r;
  }
  __device__ __forceinline__ static JM swp(const JM& o) {
    JM x; x.v = qswap(o.v); x.a = qswap(o.a); x.b = qswap(o.b); x.m = qswap(o.m);
    return x;
  }
};

// ---------------------------------------------------------------------------
// Pair-distributed net. Lane r (r = tid&1) owns output neurons {10r..10r+9}
// of every 20-wide layer; the two 10-blocks of inputs are exchanged once per
// layer via qswap. Returns the lane's owned final neuron: r=0 -> psi, r=1 -> p.
// ---------------------------------------------------------------------------
template <class J>
__device__ __forceinline__ J pair_net(const float* __restrict__ lds, int r,
                                      const J in3[3]) {
  // L1 (3->3): replicated on both lanes (tiny)
  J T[3];
#pragma unroll
  for (int j = 0; j < 3; ++j) {
    J z = J::seed(lds[OFF_L1 + j * 4 + 3]);
#pragma unroll
    for (int i = 0; i < 3; ++i) z.macc(lds[OFF_L1 + j * 4 + i], in3[i]);
    T[j] = z.chain();
  }
  // L2 (3->20): own 10 rows, each row one b128 (3 w + bias)
  const float* w2 = lds + OFF_L2 + 48 * r;
  J H[10];
#pragma unroll
  for (int jj = 0; jj < 10; ++jj) {
    J z = J::seed(w2[jj * 4 + 3]);
#pragma unroll
    for (int i = 0; i < 3; ++i) z.macc(w2[jj * 4 + i], T[i]);
    H[jj] = z.chain();
  }
  // mids (20->20) x5: phase 0 = own input block, swap, phase 1 = partner block
#pragma unroll 1
  for (int l = 0; l < 5; ++l) {
    const float* wr = lds + OFF_MID + 544 * l + 272 * r;
    J z[10];
#pragma unroll
    for (int jj = 0; jj < 10; ++jj) z[jj] = J::seed(wr[240 + jj]);
#pragma unroll
    for (int jj = 0; jj < 10; ++jj)
#pragma unroll
      for (int ii = 0; ii < 10; ++ii)
        z[jj].macc(wr[jj * 12 + ii], H[ii]);
#pragma unroll
    for (int ii = 0; ii < 10; ++ii) H[ii] = J::swp(H[ii]);
    const float* wc = wr + 120;
#pragma unroll
    for (int jj = 0; jj < 10; ++jj)
#pragma unroll
      for (int ii = 0; ii < 10; ++ii)
        z[jj].macc(wc[jj * 12 + ii], H[ii]);
#pragma unroll
    for (int jj = 0; jj < 10; ++jj) H[jj] = z[jj].chain();
  }
  // L8 (20->2): lane r computes output neuron r
  const float* w8 = lds + OFF_L8 + 48 * r;
  J z = J::seed(w8[24]);
#pragma unroll
  for (int ii = 0; ii < 10; ++ii) z.macc(w8[ii], H[ii]);
#pragma unroll
  for (int ii = 0; ii < 10; ++ii) H[ii] = J::swp(H[ii]);
#pragma unroll
  for (int ii = 0; ii < 10; ++ii) z.macc(w8[12 + ii], H[ii]);
  return z.chain();
}

// ---------------------------------------------------------------------------
// min/max helpers
// ---------------------------------------------------------------------------
__device__ __forceinline__ unsigned flipk(float f) {
  unsigned u = __float_as_uint(f);
  return (u & 0x80000000u) ? ~u : (u | 0x80000000u);
}
__device__ __forceinline__ float unflip(unsigned k) {
  unsigned u = (k & 0x80000000u) ? (k ^ 0x80000000u) : ~k;
  return __uint_as_float(u);
}

// ---------------------------------------------------------------------------
// prep: 64 blocks of minmax partials; block 0 also packs weights into ws.
// ---------------------------------------------------------------------------
__global__ void __launch_bounds__(256) prep(
    const float* __restrict__ X, unsigned* __restrict__ part,
    float* __restrict__ wt,
    const float* W1, const float* b1, const float* W2, const float* b2,
    const float* W3, const float* b3, const float* W4, const float* b4,
    const float* W5, const float* b5, const float* W6, const float* b6,
    const float* W7, const float* b7, const float* W8, const float* b8) {
  __shared__ unsigned smin[4], smax[4];
  unsigned kmin = 0xFFFFFFFFu, kmax = 0u;
  for (int i = blockIdx.x * 256 + threadIdx.x; i < NPTS; i += MM_BLOCKS * 256) {
    unsigned key = flipk(X[3 * i]);
    kmin = min(kmin, key);
    kmax = max(kmax, key);
  }
#pragma unroll
  for (int o = 32; o > 0; o >>= 1) {
    kmin = min(kmin, (unsigned)__shfl_down((int)kmin, o, 64));
    kmax = max(kmax, (unsigned)__shfl_down((int)kmax, o, 64));
  }
  int wave = threadIdx.x >> 6;
  if ((threadIdx.x & 63) == 0) { smin[wave] = kmin; smax[wave] = kmax; }
  __syncthreads();
  if (threadIdx.x == 0) {
    part[2 * blockIdx.x]     = min(min(smin[0], smin[1]), min(smin[2], smin[3]));
    part[2 * blockIdx.x + 1] = max(max(smax[0], smax[1]), max(smax[2], smax[3]));
  }

  if (blockIdx.x == 0) {
    const int t = threadIdx.x;
    const float* Wm[5] = {W3, W4, W5, W6, W7};
    const float* bm[5] = {b3, b4, b5, b6, b7};
    // mid weights: 5 layers x 2 roles x 2 chunks x 100 entries = 2000
    for (int e = t; e < 2000; e += 256) {
      int l = e / 400, rem = e % 400;
      int r = rem / 200, rem2 = rem % 200;
      int c = rem2 / 100, q = rem2 % 100;
      int jj = q / 10, ii = q % 10;
      wt[OFF_MID + 544 * l + 272 * r + 120 * c + 12 * jj + ii] =
          Wm[l][(10 * (r ^ c) + ii) * 20 + 10 * r + jj];
    }
    if (t < 100) {  // mid biases
      int l = t / 20, rem = t % 20, r = rem / 10, jj = rem % 10;
      wt[OFF_MID + 544 * l + 272 * r + 240 + jj] = bm[l][10 * r + jj];
    }
    if (t >= 128 && t < 148) {  // L2 rows
      int q = t - 128, r = q / 10, jj = q % 10;
      float* dst = wt + OFF_L2 + 48 * r + 4 * jj;
      for (int i = 0; i < 3; ++i) dst[i] = W2[i * 20 + 10 * r + jj];
      dst[3] = b2[10 * r + jj];
    }
    if (t == 148 || t == 149) {  // L8
      int r = t - 148;
      float* dst = wt + OFF_L8 + 48 * r;
      for (int c = 0; c < 2; ++c)
        for (int ii = 0; ii < 10; ++ii)
          dst[12 * c + ii] = W8[(10 * (r ^ c) + ii) * 2 + r];
      dst[24] = b8[r];
    }
    if (t == 150) {  // L1
      for (int j = 0; j < 3; ++j) {
        for (int i = 0; i < 3; ++i) wt[OFF_L1 + 4 * j + i] = W1[i * 3 + j];
        wt[OFF_L1 + 4 * j + 3] = b1[j];
      }
    }
  }
}

// ---------------------------------------------------------------------------
// main: 2 lanes per point. Grid 512 blocks x 256 thr = 2048 waves = 2/SIMD.
// __launch_bounds__(256,4) caps the allocator at 128 VGPR — the measured
// occupancy gate (R2: 128->22%; R1/R3/R4/R5: >128 -> 11%). Hard live-state
// floor here is ~105 floats, so the cap should not spill.
// ---------------------------------------------------------------------------
__global__ void __launch_bounds__(256, 4) pinn_main(
    const float* __restrict__ X, const float* __restrict__ wt,
    const unsigned* __restrict__ part,
    const float* __restrict__ lam1p, const float* __restrict__ lam2p,
    float* __restrict__ out) {
  __shared__ __align__(16) float lds[PK_TOTAL];
  for (int s = threadIdx.x; s < PK_TOTAL; s += 256) lds[s] = wt[s];
  __syncthreads();

  unsigned kminu = 0xFFFFFFFFu, kmaxu = 0u;
#pragma unroll 8
  for (int i = 0; i < MM_BLOCKS; ++i) {
    kminu = min(kminu, part[2 * i]);
    kmaxu = max(kmaxu, part[2 * i + 1]);
  }
  float lb = unflip(kminu), ub = unflip(kmaxu);
  float kk = 2.0f / (ub - lb);

  const int tid = threadIdx.x;
  const int r = tid & 1;
  const int gid = (blockIdx.x * 256 + tid) >> 1;

  float x = X[3 * gid], y = X[3 * gid + 1], tt = X[3 * gid + 2];
  float h0 = fmaf(kk, x - lb, -1.0f);
  float h1 = fmaf(kk, y - lb, -1.0f);
  float h2 = fmaf(kk, tt - lb, -1.0f);

  // J3 passes: PX(kk,0) PY(0,kk) PP(kk,kk) PM(kk,-kk)
  // lane0 keeps psi jets; p results pulled from lane1 via qpart.
  float psi_x = 0, psi_xx = 0, psi_xxx = 0;
  float psi_y = 0, psi_yy = 0, psi_yyy = 0;
  float S2p = 0, S3p = 0, S2m = 0, S3m = 0;
  float p_val = 0, p_x = 0, p_y = 0;
#pragma unroll 1
  for (int ph = 0; ph < 4; ++ph) {
    float dx = (ph == 1) ? 0.0f : kk;
    float dy = (ph == 0) ? 0.0f : ((ph == 3) ? -kk : kk);
    J3 in3[3];
    in3[0].v = h0; in3[0].c1 = dx;  in3[0].c2 = 0.f; in3[0].c3 = 0.f;
    in3[1].v = h1; in3[1].c1 = dy;  in3[1].c2 = 0.f; in3[1].c3 = 0.f;
    in3[2].v = h2; in3[2].c1 = 0.f; in3[2].c2 = 0.f; in3[2].c3 = 0.f;
    J3 O = pair_net<J3>(lds, r, in3);
    if (ph == 0) {
      psi_x = O.c1; psi_xx = O.c2; psi_xxx = O.c3;
      p_val = qpart(O.v); p_x = qpart(O.c1);
    } else if (ph == 1) {
      psi_y = O.c1; psi_yy = O.c2; psi_yyy = O.c3;
      p_y = qpart(O.c1);
    } else if (ph == 2) {
      S2p = O.c2; S3p = O.c3;
    } else {
      S2m = O.c2; S3m = O.c3;
    }
  }

  // JM passes XT, YT (psi_xt, psi_yt live on lane0's own output)
  float mxt = 0, myt = 0;
#pragma unroll 1
  for (int ph = 0; ph < 2; ++ph) {
    JM in3[3];
    in3[0].v = h0; in3[0].a = ph ? 0.0f : kk; in3[0].b = 0.f; in3[0].m = 0.f;
    in3[1].v = h1; in3[1].a = ph ? kk : 0.0f; in3[1].b = 0.f; in3[1].m = 0.f;
    in3[2].v = h2; in3[2].a = 0.f;            in3[2].b = kk;  in3[2].m = 0.f;
    JM O = pair_net<JM>(lds, r, in3);
    if (ph == 0) mxt = O.m; else myt = O.m;
  }

  if (r == 0) {
    float psi_xt = mxt, psi_yt = myt;

    // polarization identities
    float psi_xy  = 0.25f * (S2p - S2m);
    float psi_xxy = (S3p - S3m - 2.0f * psi_yyy) * (1.0f / 6.0f);
    float psi_xyy = (S3p + S3m - 2.0f * psi_xxx) * (1.0f / 6.0f);

    float u = psi_y, vv = -psi_x;
    float u_x = psi_xy,  u_y = psi_yy,  u_t = psi_yt;
    float v_x = -psi_xx, v_y = -psi_xy, v_t = -psi_xt;
    float u_xx = psi_xxy,  u_yy = psi_yyy;
    float v_xx = -psi_xxx, v_yy = -psi_xyy;

    float lam1 = lam1p[0], lam2 = lam2p[0];
    float f_u = u_t + lam1 * (u * u_x + vv * u_y) + p_x - lam2 * (u_xx + u_yy);
    float f_v = v_t + lam1 * (u * v_x + vv * v_y) + p_y - lam2 * (v_xx + v_yy);

    out[gid] = u;
    out[NPTS + gid] = vv;
    out[2 * NPTS + gid] = p_val;
    out[3 * NPTS + gid] = f_u;
    out[4 * NPTS + gid] = f_v;
  }
}

extern "C" void kernel_launch(void* const* d_in, const int* in_sizes, int n_in,
                              void* d_out, int out_size, void* d_ws, size_t ws_size,
                              hipStream_t stream) {
  (void)in_sizes; (void)n_in; (void)out_size; (void)ws_size;
  const float* X = (const float*)d_in[0];
  const float* W[8]; const float* B[8];
  for (int i = 0; i < 8; ++i) {
    W[i] = (const float*)d_in[1 + 2 * i];
    B[i] = (const float*)d_in[2 + 2 * i];
  }
  const float* lam1 = (const float*)d_in[17];
  const float* lam2 = (const float*)d_in[18];
  unsigned* part = (unsigned*)d_ws;
  float* wt = (float*)d_ws + WT_OFF;
  float* out = (float*)d_out;

  hipLaunchKernelGGL(prep, dim3(MM_BLOCKS), dim3(256), 0, stream,
                     X, part, wt,
                     W[0], B[0], W[1], B[1], W[2], B[2], W[3], B[3],
                     W[4], B[4], W[5], B[5], W[6], B[6], W[7], B[7]);
  hipLaunchKernelGGL(pinn_main, dim3(NPTS * 2 / 256), dim3(256), 0, stream,
                     X, wt, part, lam1, lam2, out);
}